// Round 1
// baseline (53.336 us; speedup 1.0000x reference)
//
#include <hip/hip_runtime.h>
#include <math.h>

// AntiAliasInterpolation2d: depthwise 13x13 Gaussian blur (zero-pad 6) on
// (32,3,512,512) fp32, then bilinear x0.25 (align_corners=False) -> (32,3,128,128).
//
// Math: Gaussian kernel is separable: k2 = outer(k1,k1)/sum(k2) = k1n (x) k1n
// with k1n = k1/sum(k1). Bilinear 512->128: src = 4j+1.5 exactly => output =
// average of blurred[4i+1..4i+2][4j+1..4j+2]. Folding the 2-tap [0.5,0.5]
// average into the 13-tap kernel gives a 14-tap kernel g (g[u] = 0.5*(k1n[u] +
// k1n[u-1])) applied at stride 4 with offset -5, zero-padded. Fully separable.

#define H 512
#define W 512
#define OH 128
#define OW 128
#define NC (32 * 3)
#define TAPS 14

struct G14 { float g[TAPS]; };

// One block per (n*c, out_row). 256 threads.
// Phase 1 (vertical): each thread accumulates 2 columns (float2) over up to 14
//   input rows with weights g[u], writes a 512-float vertically-blurred row to LDS.
// Phase 2 (horizontal): threads 0..127 each compute one output via 14 taps at
//   stride-4 offset from LDS, coalesced store.
__global__ __launch_bounds__(256) void aa_interp_kernel(
    const float* __restrict__ x, float* __restrict__ out, G14 gk) {
    const int bid = blockIdx.x;          // nc*128 + i
    const int i   = bid & (OH - 1);      // output row
    const int nc  = bid >> 7;            // image index (n*C + c)
    const int t   = threadIdx.x;         // 0..255

    const float* img = x + (size_t)nc * H * W;

    __shared__ float vrow[W];

    float a0 = 0.f, a1 = 0.f;
    const int r0 = 4 * i - 5;            // first input row for this output row
#pragma unroll
    for (int u = 0; u < TAPS; ++u) {
        const int r = r0 + u;
        if (r >= 0 && r < H) {
            const float2 v = reinterpret_cast<const float2*>(img + (size_t)r * W)[t];
            const float g = gk.g[u];
            a0 += g * v.x;
            a1 += g * v.y;
        }
    }
    reinterpret_cast<float2*>(vrow)[t] = make_float2(a0, a1);
    __syncthreads();

    if (t < OW) {
        const int c0 = 4 * t - 5;
        float acc = 0.f;
#pragma unroll
        for (int v = 0; v < TAPS; ++v) {
            const int c = c0 + v;
            if (c >= 0 && c < W) acc += gk.g[v] * vrow[c];
        }
        out[(size_t)bid * OW + t] = acc;
    }
}

extern "C" void kernel_launch(void* const* d_in, const int* in_sizes, int n_in,
                              void* d_out, int out_size, void* d_ws, size_t ws_size,
                              hipStream_t stream) {
    const float* x = (const float*)d_in[0];
    float* out = (float*)d_out;

    // Build the 14-tap fused kernel on host (deterministic; mirrors reference
    // _gaussian_kernel: sigma = 1.5, ka = 6, 13 taps, normalized).
    G14 gk;
    {
        double k1[13], s = 0.0;
        for (int d = 0; d < 13; ++d) {
            double dd = d - 6;
            k1[d] = exp(-(dd * dd) / (2.0 * 1.5 * 1.5));
            s += k1[d];
        }
        for (int u = 0; u < TAPS; ++u) {
            double lo = (u - 1 >= 0 && u - 1 < 13) ? k1[u - 1] : 0.0;
            double hi = (u < 13) ? k1[u] : 0.0;
            gk.g[u] = (float)(0.5 * (lo + hi) / s);
        }
    }

    const int blocks = NC * OH;  // 12288
    aa_interp_kernel<<<blocks, 256, 0, stream>>>(x, out, gk);
}

// Round 2
// 24.493 us; speedup vs baseline: 2.1776x; 2.1776x over previous
//
#include <hip/hip_runtime.h>
#include <math.h>

// AntiAliasInterpolation2d: depthwise 13x13 Gaussian (zero-pad 6) on
// (32,3,512,512) fp32 + bilinear x0.25 -> (32,3,128,128).
// Separable: fold the exact 2x2-average downsample into the 13-tap 1D kernel
// -> 14-tap kernel at stride 4, offset -5, applied vertically then horizontally.
//
// R1: row-tiled. One block = one (n,c) x 16 output rows. Streams 74 input rows
// once (vs 16x14=224 in R0) -> fetch ~116 MB vs 171 MB. LDS stride 528
// (+1 float per 32) makes phase-1 writes and phase-2 stride-32 reads 2-way
// bank-aliased (free). Phase 2 uses a 42-col register window: 42 LDS reads
// per thread instead of 112, all 256 threads active.

#define H 512
#define W 512
#define OH 128
#define OW 128
#define NC 96
#define TAPS 14
#define TI 16
#define NTILES (OH / TI)            // 8
#define ROWS (4 * (TI - 1) + TAPS)  // 74
#define LSTRIDE (W + W / 32)        // 528

struct G14 { float g[TAPS]; };

__global__ __launch_bounds__(256) void aa_interp_kernel(
    const float* __restrict__ x, float* __restrict__ out, G14 gk) {
    const int bid = blockIdx.x;
    const int tb  = bid & (NTILES - 1);
    const int nc  = bid >> 3;
    const int t   = threadIdx.x;

    const float* img = x + (size_t)nc * H * W;
    const int r_start = tb * (4 * TI) - 5;  // first input row of this tile

    // ---- Phase 1: vertical 14-tap at stride 4, 16 output rows at once ----
    float2 acc[TI];
#pragma unroll
    for (int io = 0; io < TI; ++io) acc[io] = make_float2(0.f, 0.f);

#pragma unroll
    for (int k = 0; k < ROWS; ++k) {
        const int r = r_start + k;
        float2 v = make_float2(0.f, 0.f);
        if (r >= 0 && r < H)
            v = reinterpret_cast<const float2*>(img + (size_t)r * W)[t];
        const int lo = (k >= TAPS) ? ((k - TAPS + 4) >> 2) : 0;  // ceil((k-13)/4)
        const int hi = ((k >> 2) < (TI - 1)) ? (k >> 2) : (TI - 1);
#pragma unroll
        for (int io = lo; io <= hi; ++io) {
            const float g = gk.g[k - 4 * io];
            acc[io].x += g * v.x;
            acc[io].y += g * v.y;
        }
    }

    __shared__ float lds[TI * LSTRIDE];
    {
        const int c0 = 2 * t, c1 = 2 * t + 1;
        const int a0 = c0 + (c0 >> 5), a1 = c1 + (c1 >> 5);
#pragma unroll
        for (int io = 0; io < TI; ++io) {
            lds[io * LSTRIDE + a0] = acc[io].x;
            lds[io * LSTRIDE + a1] = acc[io].y;
        }
    }
    __syncthreads();

    // ---- Phase 2: horizontal 14-tap at stride 4 via 42-col register window ----
    const int io = t >> 4;             // 0..15: which output row in tile
    const int j0 = (t & 15) * 8;       // 8 consecutive outputs per thread
    const float* lrow = lds + io * LSTRIDE;
    const int cb = 4 * j0 - 5;

    float win[42];
#pragma unroll
    for (int w = 0; w < 42; ++w) {
        const int c = cb + w;
        float v = 0.f;
        if (c >= 0 && c < W) v = lrow[c + (c >> 5)];
        win[w] = v;
    }

    float res[8];
#pragma unroll
    for (int jj = 0; jj < 8; ++jj) {
        float s = 0.f;
#pragma unroll
        for (int v = 0; v < TAPS; ++v) s += gk.g[v] * win[4 * jj + v];
        res[jj] = s;
    }

    float* op = out + ((size_t)nc * OH + tb * TI + io) * OW + j0;
    reinterpret_cast<float4*>(op)[0] = make_float4(res[0], res[1], res[2], res[3]);
    reinterpret_cast<float4*>(op)[1] = make_float4(res[4], res[5], res[6], res[7]);
}

extern "C" void kernel_launch(void* const* d_in, const int* in_sizes, int n_in,
                              void* d_out, int out_size, void* d_ws, size_t ws_size,
                              hipStream_t stream) {
    const float* x = (const float*)d_in[0];
    float* out = (float*)d_out;

    // 14-tap fused kernel (13-tap normalized Gaussian, sigma=1.5, convolved
    // with the exact [0.5, 0.5] bilinear-x0.25 average).
    G14 gk;
    {
        double k1[13], s = 0.0;
        for (int d = 0; d < 13; ++d) {
            double dd = d - 6;
            k1[d] = exp(-(dd * dd) / (2.0 * 1.5 * 1.5));
            s += k1[d];
        }
        for (int u = 0; u < TAPS; ++u) {
            double lo = (u - 1 >= 0 && u - 1 < 13) ? k1[u - 1] : 0.0;
            double hi = (u < 13) ? k1[u] : 0.0;
            gk.g[u] = (float)(0.5 * (lo + hi) / s);
        }
    }

    const int blocks = NC * NTILES;  // 768
    aa_interp_kernel<<<blocks, 256, 0, stream>>>(x, out, gk);
}

// Round 3
// 21.917 us; speedup vs baseline: 2.4335x; 1.1175x over previous
//
#include <hip/hip_runtime.h>
#include <math.h>

// AntiAliasInterpolation2d: depthwise 13x13 Gaussian (zero-pad 6) on
// (32,3,512,512) fp32 + bilinear x0.25 -> (32,3,128,128).
// Separable: fold the exact 2x2-average downsample into the 13-tap 1D kernel
// -> 14-tap kernel at stride 4, offset -5, vertical then horizontal.
//
// R2: 512-thread blocks (8 waves -> 24 waves/CU, was 12) to raise in-flight
// VMEM; phase-1 is one dword/lane/row (coalesced). XCD-chunked block swizzle
// (phys %8 -> same XCD gets 96 consecutive logical tiles) so the 10-row halo
// shared by adjacent tiles of an image hits that XCD's L2.

#define H 512
#define W 512
#define OH 128
#define OW 128
#define NC 96
#define TAPS 14
#define TI 16
#define NTILES (OH / TI)            // 8
#define GRID (NC * NTILES)          // 768
#define ROWS (4 * (TI - 1) + TAPS)  // 74
#define LSTRIDE (W + W / 32)        // 528

struct G14 { float g[TAPS]; };

__global__ __launch_bounds__(512) void aa_interp_kernel(
    const float* __restrict__ x, float* __restrict__ out, G14 gk) {
    // XCD-chunked swizzle: physical blocks round-robin XCDs by (bid % 8);
    // give each XCD a contiguous chunk of 96 logical tiles (12 images).
    const int bid  = (blockIdx.x & 7) * (GRID / 8) + (blockIdx.x >> 3);
    const int tb   = bid & (NTILES - 1);
    const int nc   = bid >> 3;
    const int t    = threadIdx.x;        // 0..511

    const float* img = x + (size_t)nc * H * W;
    const int r_start = tb * (4 * TI) - 5;

    // ---- Phase 1: vertical 14-tap at stride 4, 16 output rows, 1 col/thread ----
    float acc[TI];
#pragma unroll
    for (int io = 0; io < TI; ++io) acc[io] = 0.f;

#pragma unroll
    for (int k = 0; k < ROWS; ++k) {
        const int r = r_start + k;
        float v = 0.f;
        if (r >= 0 && r < H) v = img[(size_t)r * W + t];
        const int lo = (k >= TAPS) ? ((k - TAPS + 4) >> 2) : 0;
        const int hi = ((k >> 2) < (TI - 1)) ? (k >> 2) : (TI - 1);
#pragma unroll
        for (int io = lo; io <= hi; ++io) acc[io] += gk.g[k - 4 * io] * v;
    }

    __shared__ float lds[TI * LSTRIDE];
    {
        const int a = t + (t >> 5);      // +1 pad per 32: 2-way aliasing (free)
#pragma unroll
        for (int io = 0; io < TI; ++io) lds[io * LSTRIDE + a] = acc[io];
    }
    __syncthreads();

    // ---- Phase 2: horizontal 14-tap at stride 4; 4 outputs/thread ----
    const int io = t >> 5;               // 0..15 output row in tile
    const int jg = t & 31;               // 32 threads per row
    const int j0 = jg * 4;
    const float* lrow = lds + io * LSTRIDE;
    const int cb = 4 * j0 - 5;

    float win[26];                       // 4*3 + 14
#pragma unroll
    for (int w = 0; w < 26; ++w) {
        const int c = cb + w;
        float v = 0.f;
        if (c >= 0 && c < W) v = lrow[c + (c >> 5)];
        win[w] = v;
    }

    float res[4];
#pragma unroll
    for (int jj = 0; jj < 4; ++jj) {
        float s = 0.f;
#pragma unroll
        for (int v = 0; v < TAPS; ++v) s += gk.g[v] * win[4 * jj + v];
        res[jj] = s;
    }

    float* op = out + ((size_t)nc * OH + tb * TI + io) * OW + j0;
    reinterpret_cast<float4*>(op)[0] = make_float4(res[0], res[1], res[2], res[3]);
}

extern "C" void kernel_launch(void* const* d_in, const int* in_sizes, int n_in,
                              void* d_out, int out_size, void* d_ws, size_t ws_size,
                              hipStream_t stream) {
    const float* x = (const float*)d_in[0];
    float* out = (float*)d_out;

    // 14-tap fused kernel (13-tap normalized Gaussian, sigma=1.5, convolved
    // with the exact [0.5, 0.5] bilinear-x0.25 average).
    G14 gk;
    {
        double k1[13], s = 0.0;
        for (int d = 0; d < 13; ++d) {
            double dd = d - 6;
            k1[d] = exp(-(dd * dd) / (2.0 * 1.5 * 1.5));
            s += k1[d];
        }
        for (int u = 0; u < TAPS; ++u) {
            double lo = (u - 1 >= 0 && u - 1 < 13) ? k1[u - 1] : 0.0;
            double hi = (u < 13) ? k1[u] : 0.0;
            gk.g[u] = (float)(0.5 * (lo + hi) / s);
        }
    }

    aa_interp_kernel<<<GRID, 512, 0, stream>>>(x, out, gk);
}